// Round 4
// baseline (170.184 us; speedup 1.0000x reference)
//
#include <hip/hip_runtime.h>

// CARAFE-style fused upsampler: B=8, C=64, H=W=128, scale=2, ks=3.
// Single kernel. Block = 512 threads = (batch, 8x16 lo-res tile), ALL 64 ch.
// LDS: xs[64][10][19] (48.6KB) + mean tile + partials ~= 51KB -> 3 blocks/CU
// = 24 waves/CU. Channel mean computed in-block (no separate pass, x read once).

#define TB 512

__global__ __launch_bounds__(512, 6) void carafe_fused(
    const float* __restrict__ x,
    const float* __restrict__ w_off,
    const float* __restrict__ b_off,
    float* __restrict__ out)
{
    constexpr int H = 128, W = 128, HS = 256, WS = 256;
    constexpr int TH = 8, TWD = 16;     // lo-res tile
    constexpr int R = 10, CW = 18;      // halo tile dims (TH+2, TWD+2)
    constexpr int NPIX = R * CW;        // 180

    __shared__ float xs[64][R][19];     // all channels, halo 1, stride 19
    __shared__ float ms[R][19];         // mean tile
    __shared__ float msp[2][NPIX];      // per-half partial sums
    __shared__ float wc[50];
    __shared__ float bc[2];

    const int tid = threadIdx.x;
    const int bid = blockIdx.x;
    // bid = b*128 + ty*8 + tx ; 16 tile-rows x 8 tile-cols
    const int b  = bid >> 7;
    const int ty = (bid >> 3) & 15;
    const int tx = bid & 7;
    const int y0 = ty * TH, x0 = tx * TWD;

    if (tid < 50)      wc[tid] = w_off[tid];
    else if (tid < 52) bc[tid - 50] = b_off[tid - 50];

    // ---- phase 1: stage all 64 ch + partial channel sums ----
    {
        const int h = tid >> 8;          // half: channels 32h..32h+31
        const int l = tid & 255;
        if (l < NPIX) {
            const int r = l / CW, col = l - r * CW;
            const int gy = y0 - 1 + r, gx = x0 - 1 + col;
            const bool in = ((unsigned)gy < (unsigned)H) && ((unsigned)gx < (unsigned)W);
            const float* xb = x + (((size_t)b * 64 + h * 32) * H + gy) * W + gx;
            float acc = 0.0f;
            #pragma unroll
            for (int c = 0; c < 32; ++c) {
                float v = in ? xb[(size_t)c * (H * W)] : 0.0f;
                xs[h * 32 + c][r][col] = v;
                acc += v;
            }
            msp[h][l] = acc;
        }
    }
    __syncthreads();
    if (tid < NPIX) {
        const int r = tid / CW, col = tid - r * CW;
        ms[r][col] = (msp[0][tid] + msp[1][tid]) * (1.0f / 64.0f);
    }
    __syncthreads();

    // ---- phase 2: weights for a 1x4 hi-res strip, then CARAFE over 16 ch ----
    const int cc  = tid >> 7;           // 0..3 -> channel quarter
    const int rem = tid & 127;
    const int hy  = rem >> 3;           // 0..15 local hi-res row
    const int hq  = rem & 7;            // column group (4 px)
    const int yr  = hy >> 1;            // 0..7 local lo-res row
    const int Yg  = 2 * y0 + hy;
    const int Xg0 = 2 * x0 + hq * 4;

    float wgt[4][9];
    #pragma unroll
    for (int j = 0; j < 4; ++j) {
        const int lx = hq * 4 + j;      // local hi-res col 0..31

        float o0 = 0.0f, o1 = 0.0f;
        #pragma unroll
        for (int p = 0; p < 5; ++p) {
            const int mr = ((hy + p - 2) >> 1) + 1;
            #pragma unroll
            for (int q = 0; q < 5; ++q) {
                const int mc = ((lx + q - 2) >> 1) + 1;
                const float m = ms[mr][mc];
                o0 = fmaf(wc[p * 5 + q],      m, o0);
                o1 = fmaf(wc[25 + p * 5 + q], m, o1);
            }
        }
        const float off0 = tanhf(o0 + bc[0]) * 0.25f;
        const float off1 = tanhf(o1 + bc[1]) * 0.25f;
        const float s0 = ((hy & 1) ? 0.25f : -0.25f) + off0;
        const float s1 = ((lx & 1) ? 0.25f : -0.25f) + off1;

        const int my = yr + 1, mxc = (lx >> 1) + 1;
        const float mctr = ms[my][mxc];

        float lg[9];
        float lmax = -1e30f;
        #pragma unroll
        for (int k = 0; k < 9; ++k) {
            const int di = k / 3 - 1, dj = k % 3 - 1;
            const float d0 = s0 - (float)di;
            const float d1 = s1 - (float)dj;
            const float kern = 1.0f / fmaf(d0, d0, fmaf(d1, d1, 0.5f));
            const float gd = ms[my + di][mxc + dj] - mctr;
            const float g  = 1.0f / fmaf(gd, gd, 1.0f);
            lg[k] = g * kern;
            lmax = fmaxf(lmax, lg[k]);
        }
        float ssum = 0.0f;
        #pragma unroll
        for (int k = 0; k < 9; ++k) { lg[k] = __expf(lg[k] - lmax); ssum += lg[k]; }
        const float inv = 1.0f / ssum;
        #pragma unroll
        for (int k = 0; k < 9; ++k) wgt[j][k] = lg[k] * inv;
    }

    // ---- CARAFE: 16 channels per thread, 12 LDS taps shared by 4 px ----
    const int xc0 = hq * 2;
    const int c0  = cc * 16;
    float* ob = out + (((size_t)b * 64 + c0) * HS + Yg) * WS + Xg0;
    #pragma unroll 4
    for (int c = 0; c < 16; ++c) {
        float xv[3][4];
        #pragma unroll
        for (int di = 0; di < 3; ++di)
            #pragma unroll
            for (int dj = 0; dj < 4; ++dj)
                xv[di][dj] = xs[c0 + c][yr + di][xc0 + dj];
        float a[4];
        #pragma unroll
        for (int j = 0; j < 4; ++j) {
            const int px = j >> 1;
            float s = 0.0f;
            #pragma unroll
            for (int di = 0; di < 3; ++di)
                #pragma unroll
                for (int dj = 0; dj < 3; ++dj)
                    s = fmaf(wgt[j][di * 3 + dj], xv[di][px + dj], s);
            a[j] = s;
        }
        *reinterpret_cast<float4*>(ob + (size_t)c * HS * WS) =
            make_float4(a[0], a[1], a[2], a[3]);
    }
}

extern "C" void kernel_launch(void* const* d_in, const int* in_sizes, int n_in,
                              void* d_out, int out_size, void* d_ws, size_t ws_size,
                              hipStream_t stream) {
    const float* x  = (const float*)d_in[0];
    const float* w  = (const float*)d_in[1];
    const float* bo = (const float*)d_in[2];
    float* out = (float*)d_out;
    // grid: 8 batches * 16x8 tiles (8x16 lo-res each)
    carafe_fused<<<1024, TB, 0, stream>>>(x, w, bo, out);
}

// Round 5
// 79.971 us; speedup vs baseline: 2.1281x; 2.1281x over previous
//
#include <hip/hip_runtime.h>

// CARAFE-style fused upsampler: B=8, C=64, H=W=128, scale=2, ks=3.
// Single kernel. Block = 512 threads = (batch, 8x16 lo-res tile), ALL 64 ch.
// LDS ~51KB -> 2 blocks/CU = 16 waves/CU. Channel mean computed in-block.
// launch_bounds(512,4): VGPR budget 128 -- (512,6) forced 40 VGPRs and the
// 36-float weight array spilled to scratch (round 4: FETCH 316MB, WRITE 340MB).

#define TB 512

__global__ __launch_bounds__(512, 4) void carafe_fused(
    const float* __restrict__ x,
    const float* __restrict__ w_off,
    const float* __restrict__ b_off,
    float* __restrict__ out)
{
    constexpr int H = 128, W = 128, HS = 256, WS = 256;
    constexpr int TH = 8, TWD = 16;     // lo-res tile
    constexpr int R = 10, CW = 18;      // halo tile dims (TH+2, TWD+2)
    constexpr int NPIX = R * CW;        // 180

    __shared__ float xs[64][R][19];     // all channels, halo 1, stride 19
    __shared__ float ms[R][19];         // mean tile
    __shared__ float msp[2][NPIX];      // per-half partial sums
    __shared__ float wc[50];
    __shared__ float bc[2];

    const int tid = threadIdx.x;
    const int bid = blockIdx.x;
    // bid = b*128 + ty*8 + tx ; 16 tile-rows x 8 tile-cols
    const int b  = bid >> 7;
    const int ty = (bid >> 3) & 15;
    const int tx = bid & 7;
    const int y0 = ty * TH, x0 = tx * TWD;

    if (tid < 50)      wc[tid] = w_off[tid];
    else if (tid < 52) bc[tid - 50] = b_off[tid - 50];

    // ---- phase 1: stage all 64 ch + partial channel sums ----
    {
        const int h = tid >> 8;          // half: channels 32h..32h+31
        const int l = tid & 255;
        if (l < NPIX) {
            const int r = l / CW, col = l - r * CW;
            const int gy = y0 - 1 + r, gx = x0 - 1 + col;
            const bool in = ((unsigned)gy < (unsigned)H) && ((unsigned)gx < (unsigned)W);
            const float* xb = x + (((size_t)b * 64 + h * 32) * H + gy) * W + gx;
            float acc = 0.0f;
            #pragma unroll
            for (int c = 0; c < 32; ++c) {
                float v = in ? xb[(size_t)c * (H * W)] : 0.0f;
                xs[h * 32 + c][r][col] = v;
                acc += v;
            }
            msp[h][l] = acc;
        }
    }
    __syncthreads();
    if (tid < NPIX) {
        const int r = tid / CW, col = tid - r * CW;
        ms[r][col] = (msp[0][tid] + msp[1][tid]) * (1.0f / 64.0f);
    }
    __syncthreads();

    // ---- phase 2: weights for a 1x4 hi-res strip, then CARAFE over 16 ch ----
    const int cc  = tid >> 7;           // 0..3 -> channel quarter
    const int rem = tid & 127;
    const int hy  = rem >> 3;           // 0..15 local hi-res row
    const int hq  = rem & 7;            // column group (4 px)
    const int yr  = hy >> 1;            // 0..7 local lo-res row
    const int Yg  = 2 * y0 + hy;
    const int Xg0 = 2 * x0 + hq * 4;

    float wgt[4][9];
    #pragma unroll
    for (int j = 0; j < 4; ++j) {
        const int lx = hq * 4 + j;      // local hi-res col 0..31

        float o0 = 0.0f, o1 = 0.0f;
        #pragma unroll
        for (int p = 0; p < 5; ++p) {
            const int mr = ((hy + p - 2) >> 1) + 1;
            #pragma unroll
            for (int q = 0; q < 5; ++q) {
                const int mc = ((lx + q - 2) >> 1) + 1;
                const float m = ms[mr][mc];
                o0 = fmaf(wc[p * 5 + q],      m, o0);
                o1 = fmaf(wc[25 + p * 5 + q], m, o1);
            }
        }
        const float off0 = tanhf(o0 + bc[0]) * 0.25f;
        const float off1 = tanhf(o1 + bc[1]) * 0.25f;
        const float s0 = ((hy & 1) ? 0.25f : -0.25f) + off0;
        const float s1 = ((lx & 1) ? 0.25f : -0.25f) + off1;

        const int my = yr + 1, mxc = (lx >> 1) + 1;
        const float mctr = ms[my][mxc];

        float lg[9];
        float lmax = -1e30f;
        #pragma unroll
        for (int k = 0; k < 9; ++k) {
            const int di = k / 3 - 1, dj = k % 3 - 1;
            const float d0 = s0 - (float)di;
            const float d1 = s1 - (float)dj;
            const float kern = 1.0f / fmaf(d0, d0, fmaf(d1, d1, 0.5f));
            const float gd = ms[my + di][mxc + dj] - mctr;
            const float g  = 1.0f / fmaf(gd, gd, 1.0f);
            lg[k] = g * kern;
            lmax = fmaxf(lmax, lg[k]);
        }
        float ssum = 0.0f;
        #pragma unroll
        for (int k = 0; k < 9; ++k) { lg[k] = __expf(lg[k] - lmax); ssum += lg[k]; }
        const float inv = 1.0f / ssum;
        #pragma unroll
        for (int k = 0; k < 9; ++k) wgt[j][k] = lg[k] * inv;
    }

    // ---- CARAFE: 16 channels per thread, 12 LDS taps shared by 4 px ----
    const int xc0 = hq * 2;
    const int c0  = cc * 16;
    float* ob = out + (((size_t)b * 64 + c0) * HS + Yg) * WS + Xg0;
    #pragma unroll 4
    for (int c = 0; c < 16; ++c) {
        float xv[3][4];
        #pragma unroll
        for (int di = 0; di < 3; ++di)
            #pragma unroll
            for (int dj = 0; dj < 4; ++dj)
                xv[di][dj] = xs[c0 + c][yr + di][xc0 + dj];
        float a[4];
        #pragma unroll
        for (int j = 0; j < 4; ++j) {
            const int px = j >> 1;
            float s = 0.0f;
            #pragma unroll
            for (int di = 0; di < 3; ++di)
                #pragma unroll
                for (int dj = 0; dj < 3; ++dj)
                    s = fmaf(wgt[j][di * 3 + dj], xv[di][px + dj], s);
            a[j] = s;
        }
        *reinterpret_cast<float4*>(ob + (size_t)c * HS * WS) =
            make_float4(a[0], a[1], a[2], a[3]);
    }
}

extern "C" void kernel_launch(void* const* d_in, const int* in_sizes, int n_in,
                              void* d_out, int out_size, void* d_ws, size_t ws_size,
                              hipStream_t stream) {
    const float* x  = (const float*)d_in[0];
    const float* w  = (const float*)d_in[1];
    const float* bo = (const float*)d_in[2];
    float* out = (float*)d_out;
    // grid: 8 batches * 16x8 tiles (8x16 lo-res each)
    carafe_fused<<<1024, TB, 0, stream>>>(x, w, bo, out);
}

// Round 6
// 76.383 us; speedup vs baseline: 2.2280x; 1.0470x over previous
//
#include <hip/hip_runtime.h>

// CARAFE-style fused upsampler: B=8, C=64, H=W=128, scale=2, ks=3.
// K1: channel mean (block-reduced, float4 coalesced) -> d_ws.
// K2: (batch, 16x16 lo-res tile, 16-ch group); x tile staged as float4 rows
//     (cols x0-4..x0+19), LDS ~29KB -> 5 blocks/CU = 20 waves/CU.

#define TB 256

__global__ __launch_bounds__(256, 4) void mean_kernel(
    const float* __restrict__ x, float* __restrict__ mean)
{
    // block: 64 float4 pixel-groups x 4 channel-quarters (16 ch each)
    __shared__ float4 part[256];
    const int tid = threadIdx.x;
    const int bid = blockIdx.x;          // 512 blocks: b = bid>>6, blk = bid&63
    const int b   = bid >> 6;
    const int blk = bid & 63;
    const int cq  = tid >> 6;            // 0..3
    const int pg  = tid & 63;            // 0..63
    const float4* xb = (const float4*)(x + ((size_t)b * 64 + cq * 16) * 16384)
                       + blk * 64 + pg;
    float4 s = make_float4(0.f, 0.f, 0.f, 0.f);
    #pragma unroll
    for (int c = 0; c < 16; ++c) {
        float4 v = xb[(size_t)c * 4096];   // 16384/4 floats per channel plane
        s.x += v.x; s.y += v.y; s.z += v.z; s.w += v.w;
    }
    part[tid] = s;
    __syncthreads();
    if (tid < 64) {
        float4 a = part[tid], b4 = part[64 + tid], c4 = part[128 + tid], d4 = part[192 + tid];
        float4 m = make_float4((a.x + b4.x + c4.x + d4.x) * (1.f / 64),
                               (a.y + b4.y + c4.y + d4.y) * (1.f / 64),
                               (a.z + b4.z + c4.z + d4.z) * (1.f / 64),
                               (a.w + b4.w + c4.w + d4.w) * (1.f / 64));
        ((float4*)(mean + (size_t)b * 16384))[blk * 64 + tid] = m;
    }
}

__global__ __launch_bounds__(256, 4) void carafe_main(
    const float* __restrict__ x,
    const float* __restrict__ mean,
    const float* __restrict__ w_off,
    const float* __restrict__ b_off,
    float* __restrict__ out)
{
    constexpr int H = 128, W = 128, HS = 256, WS = 256;

    __shared__ float4 xs4[16][18][6];   // rows y0-1..y0+16, cols x0-4..x0+19
    __shared__ float ms[18][19];        // mean tile, cols x0-1..x0+16
    __shared__ float wc[50];
    __shared__ float bc[2];
    const float* xsf = (const float*)xs4;   // [16][18][24]

    const int tid = threadIdx.x;
    const int bid = blockIdx.x;
    // bid = b*256 + ty*32 + tx*4 + cg
    const int b  = bid >> 8;
    const int t  = bid & 255;
    const int ty = t >> 5;
    const int tx = (t >> 2) & 7;
    const int cg = t & 3;
    const int y0 = ty * 16, x0 = tx * 16;
    const int c0 = cg * 16;

    if (tid < 50)      wc[tid] = w_off[tid];
    else if (tid < 52) bc[tid - 50] = b_off[tid - 50];

    // ---- stage mean tile (zero outside image) ----
    const float* mb = mean + (size_t)b * (H * W);
    for (int idx = tid; idx < 324; idx += TB) {
        const int r = idx / 18, col = idx - r * 18;
        const int gy = y0 - 1 + r, gx = x0 - 1 + col;
        float v = 0.0f;
        if ((unsigned)gy < (unsigned)H && (unsigned)gx < (unsigned)W)
            v = mb[gy * W + gx];
        ms[r][col] = v;
    }

    // ---- stage x tile: 16 ch x 18 rows x 6 float4 (aligned, coalesced) ----
    const float* xb = x + ((size_t)b * 64 + c0) * (H * W);
    for (int idx = tid; idx < 1728; idx += TB) {
        const int c   = idx / 108;
        const int rem = idx - c * 108;
        const int r   = rem / 6;
        const int q   = rem - r * 6;
        const int gy  = y0 - 1 + r;
        const int cb  = x0 - 4 + q * 4;       // float4-aligned col base
        float4 v = make_float4(0.f, 0.f, 0.f, 0.f);
        if ((unsigned)gy < (unsigned)H && (unsigned)cb < (unsigned)W)
            v = *(const float4*)(xb + ((size_t)c * H + gy) * W + cb);
        xs4[c][r][q] = v;
    }
    __syncthreads();

    // ---- weights for a 1x4 hi-res strip ----
    const int hy  = tid >> 3;           // 0..31 local hi-res row
    const int hq  = tid & 7;            // column group (4 px)
    const int yr  = hy >> 1;            // 0..15 local lo-res row
    const int Yg  = 2 * y0 + hy;
    const int Xg0 = 2 * x0 + hq * 4;

    float wgt[4][9];
    #pragma unroll
    for (int j = 0; j < 4; ++j) {
        const int lx = hq * 4 + j;      // local hi-res col 0..31

        float o0 = 0.0f, o1 = 0.0f;
        #pragma unroll
        for (int p = 0; p < 5; ++p) {
            const int mr = ((hy + p - 2) >> 1) + 1;
            #pragma unroll
            for (int q = 0; q < 5; ++q) {
                const int mc = ((lx + q - 2) >> 1) + 1;
                const float m = ms[mr][mc];
                o0 = fmaf(wc[p * 5 + q],      m, o0);
                o1 = fmaf(wc[25 + p * 5 + q], m, o1);
            }
        }
        const float off0 = tanhf(o0 + bc[0]) * 0.25f;
        const float off1 = tanhf(o1 + bc[1]) * 0.25f;
        const float s0 = ((hy & 1) ? 0.25f : -0.25f) + off0;
        const float s1 = ((lx & 1) ? 0.25f : -0.25f) + off1;

        const int my = yr + 1, mxc = (lx >> 1) + 1;
        const float mctr = ms[my][mxc];

        float lg[9];
        float lmax = -1e30f;
        #pragma unroll
        for (int k = 0; k < 9; ++k) {
            const int di = k / 3 - 1, dj = k % 3 - 1;
            const float d0 = s0 - (float)di;
            const float d1 = s1 - (float)dj;
            const float kern = 1.0f / fmaf(d0, d0, fmaf(d1, d1, 0.5f));
            const float gd = ms[my + di][mxc + dj] - mctr;
            const float g  = 1.0f / fmaf(gd, gd, 1.0f);
            lg[k] = g * kern;
            lmax = fmaxf(lmax, lg[k]);
        }
        float ssum = 0.0f;
        #pragma unroll
        for (int k = 0; k < 9; ++k) { lg[k] = __expf(lg[k] - lmax); ssum += lg[k]; }
        const float inv = 1.0f / ssum;
        #pragma unroll
        for (int k = 0; k < 9; ++k) wgt[j][k] = lg[k] * inv;
    }

    // ---- CARAFE: 16 channels, 12 LDS taps shared by the 4 px ----
    const int xc0 = hq * 2 + 3;         // local col of first tap (x0-1 offset +4)
    float* ob = out + (((size_t)b * 64 + c0) * HS + Yg) * WS + Xg0;
    #pragma unroll 4
    for (int c = 0; c < 16; ++c) {
        float xv[3][4];
        #pragma unroll
        for (int di = 0; di < 3; ++di)
            #pragma unroll
            for (int dj = 0; dj < 4; ++dj)
                xv[di][dj] = xsf[((c * 18) + yr + di) * 24 + xc0 + dj];
        float a[4];
        #pragma unroll
        for (int j = 0; j < 4; ++j) {
            const int px = j >> 1;
            float s = 0.0f;
            #pragma unroll
            for (int di = 0; di < 3; ++di)
                #pragma unroll
                for (int dj = 0; dj < 3; ++dj)
                    s = fmaf(wgt[j][di * 3 + dj], xv[di][px + dj], s);
            a[j] = s;
        }
        *reinterpret_cast<float4*>(ob + (size_t)c * HS * WS) =
            make_float4(a[0], a[1], a[2], a[3]);
    }
}

extern "C" void kernel_launch(void* const* d_in, const int* in_sizes, int n_in,
                              void* d_out, int out_size, void* d_ws, size_t ws_size,
                              hipStream_t stream) {
    const float* x  = (const float*)d_in[0];
    const float* w  = (const float*)d_in[1];
    const float* bo = (const float*)d_in[2];
    float* out  = (float*)d_out;
    float* mean = (float*)d_ws;            // 8*128*128 floats = 512 KB

    mean_kernel<<<512, TB, 0, stream>>>(x, mean);
    // grid: 8 batches * 8x8 tiles * 4 channel groups
    carafe_main<<<2048, TB, 0, stream>>>(x, mean, w, bo, out);
}

// Round 8
// 71.990 us; speedup vs baseline: 2.3640x; 1.0610x over previous
//
#include <hip/hip_runtime.h>

// CARAFE-style fused upsampler: B=8, C=64, H=W=128, scale=2, ks=3.
// K1: channel mean (block-reduced, float4 coalesced) -> d_ws.
// K2: (batch, 16x16 lo-res tile, 16-ch group); x tile staged as float4 rows.
// vs round 6 (identical math, fewer LDS reads): 12 mean taps hoisted to
// registers (conv via parity-resolved mrp rows), CARAFE taps read as float2.

#define TB 256

__global__ __launch_bounds__(256, 4) void mean_kernel(
    const float* __restrict__ x, float* __restrict__ mean)
{
    __shared__ float4 part[256];
    const int tid = threadIdx.x;
    const int bid = blockIdx.x;          // 512 blocks: b = bid>>6, blk = bid&63
    const int b   = bid >> 6;
    const int blk = bid & 63;
    const int cq  = tid >> 6;            // 0..3
    const int pg  = tid & 63;            // 0..63
    const float4* xb = (const float4*)(x + ((size_t)b * 64 + cq * 16) * 16384)
                       + blk * 64 + pg;
    float4 s = make_float4(0.f, 0.f, 0.f, 0.f);
    #pragma unroll
    for (int c = 0; c < 16; ++c) {
        float4 v = xb[(size_t)c * 4096];
        s.x += v.x; s.y += v.y; s.z += v.z; s.w += v.w;
    }
    part[tid] = s;
    __syncthreads();
    if (tid < 64) {
        float4 a = part[tid], b4 = part[64 + tid], c4 = part[128 + tid], d4 = part[192 + tid];
        float4 m = make_float4((a.x + b4.x + c4.x + d4.x) * (1.f / 64),
                               (a.y + b4.y + c4.y + d4.y) * (1.f / 64),
                               (a.z + b4.z + c4.z + d4.z) * (1.f / 64),
                               (a.w + b4.w + c4.w + d4.w) * (1.f / 64));
        ((float4*)(mean + (size_t)b * 16384))[blk * 64 + tid] = m;
    }
}

__global__ __launch_bounds__(256, 4) void carafe_main(
    const float* __restrict__ x,
    const float* __restrict__ mean,
    const float* __restrict__ w_off,
    const float* __restrict__ b_off,
    float* __restrict__ out)
{
    constexpr int H = 128, W = 128, HS = 256, WS = 256;

    __shared__ float4 xs4[16][18][6];   // rows y0-1..y0+16, cols x0-4..x0+19
    __shared__ float ms[18][19];        // mean tile, cols x0-1..x0+16
    __shared__ float wc[50];
    __shared__ float bc[2];
    const float2* xs2 = (const float2*)xs4;   // [16][18][12] float2

    const int tid = threadIdx.x;
    const int bid = blockIdx.x;
    // bid = b*256 + ty*32 + tx*4 + cg
    const int b  = bid >> 8;
    const int t  = bid & 255;
    const int ty = t >> 5;
    const int tx = (t >> 2) & 7;
    const int cg = t & 3;
    const int y0 = ty * 16, x0 = tx * 16;
    const int c0 = cg * 16;

    if (tid < 50)      wc[tid] = w_off[tid];
    else if (tid < 52) bc[tid - 50] = b_off[tid - 50];

    // ---- stage mean tile (zero outside image) ----
    const float* mb = mean + (size_t)b * (H * W);
    for (int idx = tid; idx < 324; idx += TB) {
        const int r = idx / 18, col = idx - r * 18;
        const int gy = y0 - 1 + r, gx = x0 - 1 + col;
        float v = 0.0f;
        if ((unsigned)gy < (unsigned)H && (unsigned)gx < (unsigned)W)
            v = mb[gy * W + gx];
        ms[r][col] = v;
    }

    // ---- stage x tile: 16 ch x 18 rows x 6 float4 (aligned, coalesced) ----
    const float* xb = x + ((size_t)b * 64 + c0) * (H * W);
    for (int idx = tid; idx < 1728; idx += TB) {
        const int c   = idx / 108;
        const int rem = idx - c * 108;
        const int r   = rem / 6;
        const int q   = rem - r * 6;
        const int gy  = y0 - 1 + r;
        const int cb  = x0 - 4 + q * 4;       // float4-aligned col base
        float4 v = make_float4(0.f, 0.f, 0.f, 0.f);
        if ((unsigned)gy < (unsigned)H && (unsigned)cb < (unsigned)W)
            v = *(const float4*)(xb + ((size_t)c * H + gy) * W + cb);
        xs4[c][r][q] = v;
    }
    __syncthreads();

    // ---- per-thread 1x4 hi-res strip ----
    const int hy  = tid >> 3;           // 0..31 local hi-res row
    const int hq  = tid & 7;            // column group (4 px)
    const int yr  = hy >> 1;            // 0..15 local lo-res row
    const int podd = hy & 1;
    const int Yg  = 2 * y0 + hy;
    const int Xg0 = 2 * x0 + hq * 4;

    // hoist the 12 distinct mean taps (zero-halo semantics preserved)
    float m[3][4];
    #pragma unroll
    for (int r = 0; r < 3; ++r)
        #pragma unroll
        for (int cl = 0; cl < 4; ++cl)
            m[r][cl] = ms[yr + r][2 * hq + cl];

    // parity-resolved conv row sources (even rows {0,0,1,1,2}, odd {0,1,1,2,2})
    float mrp[5][4];
    #pragma unroll
    for (int cl = 0; cl < 4; ++cl) {
        mrp[0][cl] = m[0][cl];
        mrp[1][cl] = podd ? m[1][cl] : m[0][cl];
        mrp[2][cl] = m[1][cl];
        mrp[3][cl] = podd ? m[2][cl] : m[1][cl];
        mrp[4][cl] = m[2][cl];
    }

    float wgt[4][9];
    #pragma unroll
    for (int j = 0; j < 4; ++j) {
        float o0 = 0.f, o1 = 0.f;
        #pragma unroll
        for (int p = 0; p < 5; ++p)
            #pragma unroll
            for (int q = 0; q < 5; ++q) {
                const int cl = ((j + q - 2) >> 1) + 1;   // compile-time
                o0 = fmaf(wc[p * 5 + q],      mrp[p][cl], o0);
                o1 = fmaf(wc[25 + p * 5 + q], mrp[p][cl], o1);
            }
        const float off0 = tanhf(o0 + bc[0]) * 0.25f;
        const float off1 = tanhf(o1 + bc[1]) * 0.25f;
        const float s0 = (podd ? 0.25f : -0.25f) + off0;
        const float s1 = ((j & 1) ? 0.25f : -0.25f) + off1;

        const int jc = 1 + (j >> 1);
        const float mctr = m[1][jc];

        float lg[9];
        float lmax = -1e30f;
        #pragma unroll
        for (int k = 0; k < 9; ++k) {
            const int di = k / 3 - 1, dj = k % 3 - 1;
            const float d0 = s0 - (float)di;
            const float d1 = s1 - (float)dj;
            const float kern = 1.0f / fmaf(d0, d0, fmaf(d1, d1, 0.5f));
            const float gd = m[1 + di][jc + dj] - mctr;
            const float g  = 1.0f / fmaf(gd, gd, 1.0f);
            lg[k] = g * kern;
            lmax = fmaxf(lmax, lg[k]);
        }
        float ssum = 0.f;
        #pragma unroll
        for (int k = 0; k < 9; ++k) { lg[k] = __expf(lg[k] - lmax); ssum += lg[k]; }
        const float inv = 1.f / ssum;
        #pragma unroll
        for (int k = 0; k < 9; ++k) wgt[j][k] = lg[k] * inv;
    }

    // ---- CARAFE: 16 channels; taps = 3 float2 reads per row (8B aligned) ----
    float* ob = out + (((size_t)b * 64 + c0) * HS + Yg) * WS + Xg0;
    #pragma unroll 4
    for (int c = 0; c < 16; ++c) {
        float xv[3][4];
        #pragma unroll
        for (int r = 0; r < 3; ++r) {
            const int rb = ((c * 18) + yr + r) * 12 + hq;   // float2 index
            const float2 f0 = xs2[rb + 1];   // cols 2hq+2, 2hq+3
            const float2 f1 = xs2[rb + 2];   // cols 2hq+4, 2hq+5
            const float2 f2 = xs2[rb + 3];   // cols 2hq+6, 2hq+7
            xv[r][0] = f0.y; xv[r][1] = f1.x; xv[r][2] = f1.y; xv[r][3] = f2.x;
        }
        float a[4];
        #pragma unroll
        for (int j = 0; j < 4; ++j) {
            const int px = j >> 1;
            float s = 0.f;
            #pragma unroll
            for (int di = 0; di < 3; ++di)
                #pragma unroll
                for (int dj = 0; dj < 3; ++dj)
                    s = fmaf(wgt[j][di * 3 + dj], xv[di][px + dj], s);
            a[j] = s;
        }
        *reinterpret_cast<float4*>(ob + (size_t)c * HS * WS) =
            make_float4(a[0], a[1], a[2], a[3]);
    }
}

extern "C" void kernel_launch(void* const* d_in, const int* in_sizes, int n_in,
                              void* d_out, int out_size, void* d_ws, size_t ws_size,
                              hipStream_t stream) {
    const float* x  = (const float*)d_in[0];
    const float* w  = (const float*)d_in[1];
    const float* bo = (const float*)d_in[2];
    float* out  = (float*)d_out;
    float* mean = (float*)d_ws;            // 8*128*128 floats = 512 KB

    mean_kernel<<<512, TB, 0, stream>>>(x, mean);
    // grid: 8 batches * 8x8 tiles * 4 channel groups
    carafe_main<<<2048, TB, 0, stream>>>(x, mean, w, bo, out);
}